// Round 1
// baseline (139.022 us; speedup 1.0000x reference)
//
#include <hip/hip_runtime.h>
#include <math.h>

// Problem shape (fixed by setup_inputs): B=8192 rows, D=2048 cols, fp32.
static constexpr int Dn = 2048;
static constexpr int Bn = 8192;

__device__ __forceinline__ float dot4(float4 a, float4 b) {
    return a.x * b.x + a.y * b.y + a.z * b.z + a.w * b.w;
}

// Kernel 1: a = embed[0] / max(||embed[0]||, 1e-12);  na = max(||a||, 1e-6)
// One block of 256 threads; each thread owns 8 floats (2 x float4).
__global__ __launch_bounds__(256) void k_anchor(const float* __restrict__ embed,
                                                float* __restrict__ a_out,
                                                float* __restrict__ na_out) {
    __shared__ float red[8];
    const int t = threadIdx.x;
    const int lane = t & 63, wave = t >> 6;

    float4 v0 = reinterpret_cast<const float4*>(embed)[t];        // d = 4t..4t+3
    float4 v1 = reinterpret_cast<const float4*>(embed)[t + 256];  // d = 1024+4t..

    float ss = dot4(v0, v0) + dot4(v1, v1);
#pragma unroll
    for (int o = 32; o > 0; o >>= 1) ss += __shfl_down(ss, o, 64);
    if (lane == 0) red[wave] = ss;
    __syncthreads();
    if (t == 0) red[4] = red[0] + red[1] + red[2] + red[3];
    __syncthreads();

    const float inv = 1.0f / fmaxf(sqrtf(red[4]), 1e-12f);
    float4 a0, a1;
    a0.x = v0.x * inv; a0.y = v0.y * inv; a0.z = v0.z * inv; a0.w = v0.w * inv;
    a1.x = v1.x * inv; a1.y = v1.y * inv; a1.z = v1.z * inv; a1.w = v1.w * inv;
    reinterpret_cast<float4*>(a_out)[t]       = a0;
    reinterpret_cast<float4*>(a_out)[t + 256] = a1;

    // na from the stored fp32 normalized values (faithful to reference)
    float ssa = dot4(a0, a0) + dot4(a1, a1);
#pragma unroll
    for (int o = 32; o > 0; o >>= 1) ssa += __shfl_down(ssa, o, 64);
    __syncthreads();  // all reads of red[0..4] done before re-use
    if (lane == 0) red[wave] = ssa;
    __syncthreads();
    if (t == 0) *na_out = fmaxf(sqrtf(red[0] + red[1] + red[2] + red[3]), 1e-6f);
}

// Kernel 2: per row j: neg[j] = -(ee[j]·a) / (na * max(||ee[j]||,1e-6)) / T
// One 256-thread block per row; float4 coalesced loads; the memory-bound pass.
__global__ __launch_bounds__(256) void k_rows(const float* __restrict__ ee,
                                              const float* __restrict__ a,
                                              const float* __restrict__ na_p,
                                              float* __restrict__ neg_out) {
    __shared__ float rd[4], rs[4];
    const int t = threadIdx.x;
    const int lane = t & 63, wave = t >> 6;
    const int j = blockIdx.x;

    const float4* row = reinterpret_cast<const float4*>(ee + (size_t)j * Dn);
    const float4* av  = reinterpret_cast<const float4*>(a);

    float4 e0 = row[t], e1 = row[t + 256];
    float4 a0 = av[t],  a1 = av[t + 256];

    float dot = dot4(e0, a0) + dot4(e1, a1);
    float ss  = dot4(e0, e0) + dot4(e1, e1);
#pragma unroll
    for (int o = 32; o > 0; o >>= 1) {
        dot += __shfl_down(dot, o, 64);
        ss  += __shfl_down(ss,  o, 64);
    }
    if (lane == 0) { rd[wave] = dot; rs[wave] = ss; }
    __syncthreads();
    if (t == 0) {
        const float dtot = rd[0] + rd[1] + rd[2] + rd[3];
        const float stot = rs[0] + rs[1] + rs[2] + rs[3];
        const float nb   = fmaxf(sqrtf(stot), 1e-6f);
        const float cosv = dtot / ((*na_p) * nb);
        neg_out[j] = -cosv * 10.0f;  // 1/T, T = 0.1
    }
}

// Kernel 3: fp64 final reduction over j != 0.
//   E0 = 1e-12 + sum exp(neg[j]);  C0 = 1e-12 + l0 * sum labels[j]
//   L0 = -(l0/C0) * (sum labels[j]*neg[j] - log(E0) * sum labels[j])
//   out = L0 / B
__global__ __launch_bounds__(256) void k_final(const float* __restrict__ neg,
                                               const float* __restrict__ labels,
                                               float* __restrict__ out) {
    __shared__ double rE[4], rL[4], rN[4];
    const int t = threadIdx.x;
    const int lane = t & 63, wave = t >> 6;

    double sE = 0.0, sL = 0.0, sN = 0.0;
    for (int j = t; j < Bn; j += 256) {
        if (j == 0) continue;  // mask: exclude j == i == 0
        const float ng = neg[j];
        const float lb = labels[j];
        sE += (double)expf(ng);
        sL += (double)lb;
        sN += (double)lb * (double)ng;
    }
#pragma unroll
    for (int o = 32; o > 0; o >>= 1) {
        sE += __shfl_down(sE, o, 64);
        sL += __shfl_down(sL, o, 64);
        sN += __shfl_down(sN, o, 64);
    }
    if (lane == 0) { rE[wave] = sE; rL[wave] = sL; rN[wave] = sN; }
    __syncthreads();
    if (t == 0) {
        const double E0 = 1e-12 + rE[0] + rE[1] + rE[2] + rE[3];
        const double S2 = rL[0] + rL[1] + rL[2] + rL[3];
        const double S3 = rN[0] + rN[1] + rN[2] + rN[3];
        const double l0 = (double)labels[0];
        const double C0 = 1e-12 + l0 * S2;
        const double L0 = -(l0 / C0) * (S3 - log(E0) * S2);
        out[0] = (float)(L0 / (double)Bn);
    }
}

extern "C" void kernel_launch(void* const* d_in, const int* in_sizes, int n_in,
                              void* d_out, int out_size, void* d_ws, size_t ws_size,
                              hipStream_t stream) {
    const float* embed  = (const float*)d_in[0];  // [B, D] — only row 0 used
    const float* ee     = (const float*)d_in[1];  // [B, D]
    const float* labels = (const float*)d_in[2];  // [B]
    float* out = (float*)d_out;

    // Workspace layout (fp32): a[0..2047], na at [2048], neg at [2560..2560+8191]
    float* ws  = (float*)d_ws;
    float* a   = ws;
    float* na  = ws + 2048;
    float* neg = ws + 2560;

    k_anchor<<<1, 256, 0, stream>>>(embed, a, na);
    k_rows<<<Bn, 256, 0, stream>>>(ee, a, na, neg);
    k_final<<<1, 256, 0, stream>>>(neg, labels, out);
}

// Round 2
// 128.369 us; speedup vs baseline: 1.0830x; 1.0830x over previous
//
#include <hip/hip_runtime.h>
#include <math.h>

// Problem shape (fixed by setup_inputs): B=8192 rows, D=2048 cols, fp32.
static constexpr int Dn = 2048;
static constexpr int Bn = 8192;
static constexpr int NBLK  = 1024;      // 256 threads each -> 4096 waves
static constexpr int NWAVE = NBLK * 4;  // 2 rows per wave

__device__ __forceinline__ float dot4(float4 a, float4 b) {
    return a.x * b.x + a.y * b.y + a.z * b.z + a.w * b.w;
}

// Fused main kernel, wave-per-row:
//  - every wave independently computes the normalized anchor a = embed[0]/max(||.||,1e-12)
//    into registers (8 KB read, L1/L2-hot; deterministic & identical across waves)
//  - per row j: dot(ee[j], a) and ||ee[j]||^2 via in-lane fma over 8 float4 steps,
//    then a 6-step __shfl_xor butterfly (no LDS, no barriers)
//  - lane 0 accumulates fp64 partials of sum(exp(neg)), sum(labels), sum(labels*neg)
//    over its rows (j != 0 masked), writes 3 doubles per wave.
__global__ __launch_bounds__(256) void k_main(const float* __restrict__ embed,
                                              const float* __restrict__ ee,
                                              const float* __restrict__ labels,
                                              double* __restrict__ part) {
    const int t    = threadIdx.x;
    const int lane = t & 63;
    const int wv   = ((int)blockIdx.x << 2) | (t >> 6);  // global wave id

    // ---- anchor fragment: lane owns float4 columns {s*64 + lane}, s = 0..7 ----
    const float4* e0 = reinterpret_cast<const float4*>(embed);
    float4 av[8];
    float ss = 0.f;
#pragma unroll
    for (int s = 0; s < 8; ++s) {
        av[s] = e0[(s << 6) + lane];
        ss += dot4(av[s], av[s]);
    }
#pragma unroll
    for (int o = 32; o > 0; o >>= 1) ss += __shfl_xor(ss, o, 64);
    const float inv = 1.0f / fmaxf(sqrtf(ss), 1e-12f);

    float ssa = 0.f;
#pragma unroll
    for (int s = 0; s < 8; ++s) {
        av[s].x *= inv; av[s].y *= inv; av[s].z *= inv; av[s].w *= inv;
        ssa += dot4(av[s], av[s]);
    }
#pragma unroll
    for (int o = 32; o > 0; o >>= 1) ssa += __shfl_xor(ssa, o, 64);
    const float na = fmaxf(sqrtf(ssa), 1e-6f);  // = max(||a||, 1e-6), cos eps

    // ---- row loop: 2 rows per wave ----
    double sE = 0.0, sL = 0.0, sN = 0.0;
    for (int j = wv; j < Bn; j += NWAVE) {
        const float4* row = reinterpret_cast<const float4*>(ee + (size_t)j * Dn);
        float dt = 0.f, sr = 0.f;
#pragma unroll
        for (int s = 0; s < 8; ++s) {
            const float4 r = row[(s << 6) + lane];
            dt += dot4(r, av[s]);
            sr += dot4(r, r);
        }
#pragma unroll
        for (int o = 32; o > 0; o >>= 1) {
            dt += __shfl_xor(dt, o, 64);
            sr += __shfl_xor(sr, o, 64);
        }
        if (lane == 0 && j != 0) {
            const float nb  = fmaxf(sqrtf(sr), 1e-6f);
            const float neg = -10.0f * dt / (na * nb);   // -cos/T, T = 0.1
            const double lb = (double)labels[j];
            sE += (double)expf(neg);
            sL += lb;
            sN += lb * (double)neg;
        }
    }
    if (lane == 0) {
        part[wv]             = sE;   // SoA layout for coalesced finisher reads
        part[NWAVE + wv]     = sL;
        part[2 * NWAVE + wv] = sN;
    }
}

// Finisher: 1 block, fp64 reduce of 4096 wave-partials, then the scalar math:
//   E0 = 1e-12 + SE;  C0 = 1e-12 + l0*SL
//   L0 = -(l0/C0) * (SN - log(E0)*SL);  out = L0/B
__global__ __launch_bounds__(256) void k_final(const double* __restrict__ part,
                                               const float* __restrict__ labels,
                                               float* __restrict__ out) {
    __shared__ double rE[4], rL[4], rN[4];
    const int t = threadIdx.x;
    const int lane = t & 63, wave = t >> 6;

    double sE = 0.0, sL = 0.0, sN = 0.0;
    for (int i = t; i < NWAVE; i += 256) {
        sE += part[i];
        sL += part[NWAVE + i];
        sN += part[2 * NWAVE + i];
    }
#pragma unroll
    for (int o = 32; o > 0; o >>= 1) {
        sE += __shfl_down(sE, o, 64);
        sL += __shfl_down(sL, o, 64);
        sN += __shfl_down(sN, o, 64);
    }
    if (lane == 0) { rE[wave] = sE; rL[wave] = sL; rN[wave] = sN; }
    __syncthreads();
    if (t == 0) {
        const double E0 = 1e-12 + rE[0] + rE[1] + rE[2] + rE[3];
        const double S2 = rL[0] + rL[1] + rL[2] + rL[3];
        const double S3 = rN[0] + rN[1] + rN[2] + rN[3];
        const double l0 = (double)labels[0];
        const double C0 = 1e-12 + l0 * S2;
        const double L0 = -(l0 / C0) * (S3 - log(E0) * S2);
        out[0] = (float)(L0 / (double)Bn);
    }
}

extern "C" void kernel_launch(void* const* d_in, const int* in_sizes, int n_in,
                              void* d_out, int out_size, void* d_ws, size_t ws_size,
                              hipStream_t stream) {
    const float* embed  = (const float*)d_in[0];  // [B, D] — only row 0 used
    const float* ee     = (const float*)d_in[1];  // [B, D]
    const float* labels = (const float*)d_in[2];  // [B]
    float* out = (float*)d_out;

    double* part = (double*)d_ws;  // 3 * NWAVE doubles = 96 KB, fully overwritten

    k_main<<<NBLK, 256, 0, stream>>>(embed, ee, labels, part);
    k_final<<<1, 256, 0, stream>>>(part, labels, out);
}